// Round 12
// baseline (154.039 us; speedup 1.0000x reference)
//
// R12: R11 (best, 149.96 us) + attn XCD-chunked swizzle (T1, 768 = 8 x 96,
// bijective). Mechanism: default RR dispatch duplicates每 head's K/V across
// all 8 per-XCD L2s (FETCH 52.3 MB vs 18.9 MB footprint); chunking gives
// XCD i heads 3i..3i+2 (1.5 MB working set, L2-fit) -> K/V fetched once,
// and the per-iter vmcnt barrier drains hit L2 (~200cy) not L3 (~450cy).
// Pure index permutation: correctness-invariant.
// Ledger: no VGPR cap (R2); V LDS-staged (R3); >=12 waves/CU (R7); BK=64
// (R8); P stride 64 (R10); V-hoist unproven-alone (R9/R10).
#include <hip/hip_runtime.h>
#include <math.h>

#define B_SZ 2
#define S_SZ 2048
#define D_SZ 768
#define NH   12
#define HD   64
#define BH_T (B_SZ * NH)      // 24
#define M_TOT (B_SZ * S_SZ)   // 4096

using bfrag = __attribute__((ext_vector_type(8))) short;   // 8 bf16 (4 VGPRs)
using ffrag = __attribute__((ext_vector_type(4))) float;   // 4 fp32 acc

__device__ __forceinline__ unsigned short f2bf(float f) {      // RNE
    unsigned int u = __float_as_uint(f);
    u += 0x7fffu + ((u >> 16) & 1u);
    return (unsigned short)(u >> 16);
}

// packed f32x2 -> bf16x2 (RNE), one VALU op. lo -> D[15:0], hi -> D[31:16].
__device__ __forceinline__ unsigned cvtpk(float lo, float hi) {
    unsigned r;
    asm("v_cvt_pk_bf16_f32 %0, %1, %2" : "=v"(r) : "v"(lo), "v"(hi));
    return r;
}

// exp2 on the VALU: v_exp_f32 computes 2^x natively; log2(e) is pre-folded
// into the Q scale (proj) and fma'd onto the mask (attn).
__device__ __forceinline__ float fexp2(float x) {
#if __has_builtin(__builtin_amdgcn_exp2f)
    return __builtin_amdgcn_exp2f(x);
#else
    float r;
    asm("v_exp_f32 %0, %1" : "=v"(r) : "v"(x));
    return r;
#endif
}

// async global->LDS, 16B per lane; no VGPR round-trip.
__device__ __forceinline__ void async16(void* lds, const void* gp) {
    __builtin_amdgcn_global_load_lds(
        (const __attribute__((address_space(1))) unsigned int*)gp,
        (__attribute__((address_space(3))) unsigned int*)lds,
        16, 0, 0);
}

// ---------------------------------------------------------------------------
// prep: fused  (a) v1 fp32->bf16   (b) W [k][n] fp32 -> Wt [n][k] bf16 x3
// ---------------------------------------------------------------------------
__global__ __launch_bounds__(256) void prep(
    const float* __restrict__ v1,
    const float* __restrict__ Wq, const float* __restrict__ Wk,
    const float* __restrict__ Wv,
    unsigned short* __restrict__ v1b, unsigned short* __restrict__ Wt) {
    __shared__ float tile[64][65];
    const int bx = blockIdx.x;
    const int t = threadIdx.x;
    if (bx < 3072) {
        int i = (bx * 256 + t) * 4;
        float4 v = *(const float4*)&v1[i];
        ushort4 o;
        o.x = f2bf(v.x); o.y = f2bf(v.y); o.z = f2bf(v.z); o.w = f2bf(v.w);
        *(ushort4*)&v1b[i] = o;
    } else {
        int r = bx - 3072;               // 0..431
        int z = r / 144;
        int rr = r % 144;
        int n0 = (rr % 12) * 64, k0 = (rr / 12) * 64;
        const float* W = (z == 0) ? Wq : (z == 1) ? Wk : Wv;
        unsigned short* dst = Wt + (size_t)z * D_SZ * D_SZ;
        #pragma unroll
        for (int i = 0; i < 16; ++i) {
            int flat = i * 256 + t;
            int rr2 = flat >> 6, c = flat & 63;
            tile[rr2][c] = W[(size_t)(k0 + rr2) * D_SZ + n0 + c];
        }
        __syncthreads();
        #pragma unroll
        for (int i = 0; i < 16; ++i) {
            int flat = i * 256 + t;
            int rr2 = flat >> 6, c = flat & 63;
            dst[(size_t)(n0 + rr2) * D_SZ + k0 + c] = f2bf(tile[c][rr2]);
        }
    }
}

// ---------------------------------------------------------------------------
// QKV projection (R11-verified): 128x128 tile, BK=64, dbuf LDS via async16,
// XCD-chunked block swizzle (576 % 8 == 0; each XCD: one z, 12 y, 6 x ->
// 3.6 MB working set fits 4 MB L2).
// z<2 (Q,K): swapped operands -> lane holds 4 consecutive n; Q scaled by
// (1/8)*log2(e). z==2 (V): lane holds 4 consecutive tokens -> V^T output.
// LDS: 2 x (A 128x64 + B 128x64) bf16 = 64 KB -> 2 blocks/CU.
// ---------------------------------------------------------------------------
#define RP_LD 136

__global__ __launch_bounds__(256) void proj_gemm(
    const unsigned short* __restrict__ Ab,    // v1 bf16 [4096][768]
    const unsigned short* __restrict__ Wt,    // [3][768 n][768 k]
    const float* __restrict__ bq, const float* __restrict__ bk_,
    const float* __restrict__ bv_,
    unsigned short* __restrict__ Qb, unsigned short* __restrict__ Kb,
    unsigned short* __restrict__ Vtb) {
    // XCD-chunked bijective swizzle (T1/m204): nwg = 576, 576 % 8 == 0.
    const int orig = blockIdx.x + 6 * blockIdx.y + 192 * blockIdx.z;
    const int wg = (orig & 7) * 72 + (orig >> 3);
    const int bxi = wg % 6;
    const int byi = (wg / 6) % 32;
    const int z = wg / 192;

    const unsigned short* Bt = Wt + (size_t)z * D_SZ * D_SZ;
    const float* bias = (z == 0) ? bq : (z == 1) ? bk_ : bv_;

    __shared__ __attribute__((aligned(16)))
        unsigned short smem[2][128 * 64 + 128 * 64];   // 64 KB dbuf
    const int t = threadIdx.x;
    const int lane = t & 63;
    const int w = t >> 6;
    const int wm = w & 1, wn = w >> 1;
    const int col = lane & 15;
    const int quad = lane >> 4;
    const int m0 = byi * 128;
    const int n0 = bxi * 128;
    const int wbase = t & ~63;

    ffrag acc[4][4];
    #pragma unroll
    for (int i = 0; i < 4; ++i)
        #pragma unroll
        for (int j = 0; j < 4; ++j) { ffrag zf = {0.f, 0.f, 0.f, 0.f}; acc[i][j] = zf; }

    // prologue: stage k0=0 into buf 0
    #pragma unroll
    for (int i = 0; i < 4; ++i) {
        int c = i * 256 + t;
        int row = c >> 3;
        int gcol = ((c & 7) ^ (row & 7)) * 8;
        async16(&smem[0][(size_t)(i * 256 + wbase) * 8],
                &Ab[(size_t)(m0 + row) * D_SZ + gcol]);
    }
    #pragma unroll
    for (int i = 0; i < 4; ++i) {
        int c = i * 256 + t;
        int row = c >> 3;
        int gcol = ((c & 7) ^ (row & 7)) * 8;
        async16(&smem[0][128 * 64 + (size_t)(i * 256 + wbase) * 8],
                &Bt[(size_t)(n0 + row) * D_SZ + gcol]);
    }

    const int nIter = D_SZ / 64;   // 12
    for (int it = 0; it < nIter; ++it) {
        const int cur = it & 1;
        __syncthreads();           // drains buf[cur] loads (full prev compute)
        if (it + 1 < nIter) {      // prefetch next panel into buf[cur^1]
            const int kn = (it + 1) * 64;
            #pragma unroll
            for (int i = 0; i < 4; ++i) {
                int c = i * 256 + t;
                int row = c >> 3;
                int gcol = ((c & 7) ^ (row & 7)) * 8;
                async16(&smem[cur ^ 1][(size_t)(i * 256 + wbase) * 8],
                        &Ab[(size_t)(m0 + row) * D_SZ + kn + gcol]);
            }
            #pragma unroll
            for (int i = 0; i < 4; ++i) {
                int c = i * 256 + t;
                int row = c >> 3;
                int gcol = ((c & 7) ^ (row & 7)) * 8;
                async16(&smem[cur ^ 1][128 * 64 + (size_t)(i * 256 + wbase) * 8],
                        &Bt[(size_t)(n0 + row) * D_SZ + kn + gcol]);
            }
        }
        const unsigned short* As = &smem[cur][0];
        const unsigned short* Bs = &smem[cur][128 * 64];
        #pragma unroll
        for (int kk = 0; kk < 64; kk += 32) {
            const int cc = (kk >> 3) + quad;
            bfrag a[4], b[4];
            #pragma unroll
            for (int mi = 0; mi < 4; ++mi) {
                int row = wm * 64 + mi * 16 + col;
                a[mi] = *(const bfrag*)&As[row * 64 + ((cc ^ (row & 7)) * 8)];
            }
            #pragma unroll
            for (int ni = 0; ni < 4; ++ni) {
                int row = wn * 64 + ni * 16 + col;
                b[ni] = *(const bfrag*)&Bs[row * 64 + ((cc ^ (row & 7)) * 8)];
            }
            if (z == 2) {
                #pragma unroll
                for (int mi = 0; mi < 4; ++mi)
                    #pragma unroll
                    for (int ni = 0; ni < 4; ++ni)
                        acc[mi][ni] = __builtin_amdgcn_mfma_f32_16x16x32_bf16(
                            a[mi], b[ni], acc[mi][ni], 0, 0, 0);
            } else {
                #pragma unroll
                for (int mi = 0; mi < 4; ++mi)
                    #pragma unroll
                    for (int ni = 0; ni < 4; ++ni)
                        acc[mi][ni] = __builtin_amdgcn_mfma_f32_16x16x32_bf16(
                            b[ni], a[mi], acc[mi][ni], 0, 0, 0);
            }
        }
    }

    __syncthreads();   // reuse smem as repack tile (128 x RP_LD shorts)
    unsigned short* rp = &smem[0][0];

    if (z < 2) {
        // Q: fold 1/sqrt(hd) * log2(e) so softmax is a bare exp2
        const float sc = (z == 0) ? 0.18033688f : 1.0f;
        #pragma unroll
        for (int mi = 0; mi < 4; ++mi) {
            int m_local = wm * 64 + mi * 16 + col;             // token
            #pragma unroll
            for (int ni = 0; ni < 4; ++ni) {
                int n_base = wn * 64 + ni * 16 + quad * 4;     // 4 consecutive n
                float4 b4 = *(const float4*)&bias[n0 + n_base];
                uint2 pk;
                pk.x = (unsigned)f2bf((acc[mi][ni][0] + b4.x) * sc) |
                       ((unsigned)f2bf((acc[mi][ni][1] + b4.y) * sc) << 16);
                pk.y = (unsigned)f2bf((acc[mi][ni][2] + b4.z) * sc) |
                       ((unsigned)f2bf((acc[mi][ni][3] + b4.w) * sc) << 16);
                *(uint2*)&rp[m_local * RP_LD + n_base] = pk;
            }
        }
        __syncthreads();
        unsigned short* Out = (z == 0) ? Qb : Kb;
        #pragma unroll
        for (int j = 0; j < 8; ++j) {           // 128 rows x 16 chunks
            int flat = j * 256 + t;
            int row = flat >> 4;                // token (0..127)
            int ch = flat & 15;                 // 16B chunk within 128 n
            uint4 vv = *(const uint4*)&rp[row * RP_LD + ch * 8];
            int m = m0 + row;
            int bb = m >> 11, s = m & 2047;
            int h = (n0 >> 6) + (ch >> 3);
            int d = (ch & 7) * 8;
            *(uint4*)&Out[((size_t)(bb * NH + h) * S_SZ + s) * HD + d] = vv;
        }
    } else {
        #pragma unroll
        for (int ni = 0; ni < 4; ++ni) {
            int n_local = wn * 64 + ni * 16 + col;             // d index (0..127)
            float bvv = bias[n0 + n_local];
            #pragma unroll
            for (int mi = 0; mi < 4; ++mi) {
                int m_base = wm * 64 + mi * 16 + quad * 4;     // 4 consecutive tokens
                uint2 pk;
                pk.x = (unsigned)f2bf(acc[mi][ni][0] + bvv) |
                       ((unsigned)f2bf(acc[mi][ni][1] + bvv) << 16);
                pk.y = (unsigned)f2bf(acc[mi][ni][2] + bvv) |
                       ((unsigned)f2bf(acc[mi][ni][3] + bvv) << 16);
                *(uint2*)&rp[n_local * RP_LD + m_base] = pk;
            }
        }
        __syncthreads();
        #pragma unroll
        for (int j = 0; j < 8; ++j) {           // 128 rows x 16 chunks
            int flat = j * 256 + t;
            int row = flat >> 4;                // n index (0..127)
            int ch = flat & 15;                 // 16B chunk within 128 tokens
            uint4 vv = *(const uint4*)&rp[row * RP_LD + ch * 8];
            int n = n0 + row;
            int h = n >> 6, d = n & 63;
            int m = m0 + ch * 8;
            int bb = m >> 11, s = m & 2047;
            *(uint4*)&Vtb[((size_t)(bb * NH + h) * HD + d) * S_SZ + s] = vv;
        }
    }
}

// ---------------------------------------------------------------------------
// Flash attention (R6/R8-verified body, 55.4 us): 256 threads (4 waves x 16
// q-rows), 64-key tiles, K/V LDS dbuf via async16, swapped QK^T, cvt_pk P
// pack, x2-unrolled loop, setprio. P stride 64 (R10: 72 broke XOR reads).
// R12: XCD-chunked block swizzle — XCD i owns heads 3i..3i+2 (1.5 MB K/V
// working set per L2); barrier drains hit L2 instead of L3.
// ---------------------------------------------------------------------------
__device__ __forceinline__ void attn_iter(
    int it, int cur,
    unsigned short (&Ks)[2][64 * 64], unsigned short (&Vs)[2][64 * 64],
    unsigned short* Pw,
    const unsigned short* Kg, const unsigned short* Vg, const float* mrow,
    const int (&srw)[2], const int (&sgc)[2], int wbase, int col, int quad,
    const bfrag (&aq)[2], float4 (&mc)[4], float4 (&mn)[4],
    ffrag (&o)[4], float& lsum) {
    const int nIter = S_SZ / 64;
    __syncthreads();               // drains buf[cur] (loads ran during prev compute)
    if (it + 1 < nIter) {          // prefetch next tile into buf[cur^1]
        const int kn = (it + 1) * 64;
        #pragma unroll
        for (int i = 0; i < 2; ++i) {
            async16(&Ks[cur ^ 1][(size_t)(i * 256 + wbase) * 8],
                    &Kg[(size_t)(kn + srw[i]) * HD + sgc[i]]);
            async16(&Vs[cur ^ 1][(size_t)(i * 256 + wbase) * 8],
                    &Vg[(size_t)srw[i] * S_SZ + kn + sgc[i]]);
        }
        #pragma unroll
        for (int ni = 0; ni < 4; ++ni)
            mn[ni] = *(const float4*)&mrow[kn + ni * 16 + quad * 4];
    }

    // S^T = K Q^T: lane holds S[key=ni*16+quad*4+r][q=w*16+col].
    // kk=0 peeled with literal-zero C (no per-iter zero-init movs).
    ffrag s[4];
    __builtin_amdgcn_s_setprio(1);
    #pragma unroll
    for (int ni = 0; ni < 4; ++ni) {
        int brow = ni * 16 + col;
        bfrag bk0 = *(const bfrag*)&Ks[cur][brow * 64 + ((quad ^ (brow & 7)) * 8)];
        ffrag zf = {0.f, 0.f, 0.f, 0.f};
        s[ni] = __builtin_amdgcn_mfma_f32_16x16x32_bf16(bk0, aq[0], zf, 0, 0, 0);
    }
    #pragma unroll
    for (int ni = 0; ni < 4; ++ni) {
        int brow = ni * 16 + col;
        bfrag bk1 = *(const bfrag*)&Ks[cur][brow * 64 + (((4 + quad) ^ (brow & 7)) * 8)];
        s[ni] = __builtin_amdgcn_mfma_f32_16x16x32_bf16(bk1, aq[1], s[ni], 0, 0, 0);
    }
    __builtin_amdgcn_s_setprio(0);

    // p = 2^(s + m*log2e); lane-local l; pack via cvt_pk; 4 x ds_write_b64
    #pragma unroll
    for (int ni = 0; ni < 4; ++ni) {
        float4 m4 = mc[ni];
        float p0 = fexp2(fmaf(1.44269504f, m4.x, s[ni][0]));
        float p1 = fexp2(fmaf(1.44269504f, m4.y, s[ni][1]));
        float p2 = fexp2(fmaf(1.44269504f, m4.z, s[ni][2]));
        float p3 = fexp2(fmaf(1.44269504f, m4.w, s[ni][3]));
        lsum += ((p0 + p1) + (p2 + p3));
        uint2 pkv;
        pkv.x = cvtpk(p0, p1);
        pkv.y = cvtpk(p2, p3);
        int c = ni * 2 + (quad >> 1);      // key chunk (key>>3)
        *(uint2*)&Pw[col * 64 + ((c ^ (col & 7)) * 8) + (quad & 1) * 4] = pkv;
    }

    // O += P @ V  (P read addressing identical to verified layout)
    __builtin_amdgcn_s_setprio(1);
    #pragma unroll
    for (int kk = 0; kk < 2; ++kk) {
        const int cc = kk * 4 + quad;
        bfrag ap = *(const bfrag*)&Pw[col * 64 + ((cc ^ (col & 7)) * 8)];
        #pragma unroll
        for (int di = 0; di < 4; ++di) {
            int vrow = di * 16 + col;
            bfrag bv8 = *(const bfrag*)&Vs[cur][vrow * 64 + ((cc ^ (vrow & 7)) * 8)];
            o[di] = __builtin_amdgcn_mfma_f32_16x16x32_bf16(ap, bv8, o[di], 0, 0, 0);
        }
    }
    __builtin_amdgcn_s_setprio(0);
}

__global__ __launch_bounds__(256) void attn_mfma(
    const unsigned short* __restrict__ Qb, const unsigned short* __restrict__ Kb,
    const unsigned short* __restrict__ Vt, const float* __restrict__ mask,
    float* __restrict__ out) {
    __shared__ unsigned short Ks[2][64 * 64];  // 16 KB [key][d] swizzled
    __shared__ unsigned short Vs[2][64 * 64];  // 16 KB [d][key] swizzled
    __shared__ unsigned short Ps[4][16 * 64];  // 8 KB wave-private [q][key] swz

    const int t = threadIdx.x;
    const int lane = t & 63;
    const int w = t >> 6;
    const int col = lane & 15;
    const int quad = lane >> 4;

    // XCD-chunked bijective swizzle (nwg = 768 = 8 x 96): XCD i gets wg in
    // [96i, 96(i+1)) = heads 3i..3i+2, all 32 q-blocks of each.
    const int orig = blockIdx.x + 32 * blockIdx.y;
    const int wg = (orig & 7) * 96 + (orig >> 3);
    const int q0 = (wg & 31) * 64;
    const int bh = wg >> 5;
    const int b = bh / NH, h = bh % NH;
    const int wbase = t & ~63;

    const unsigned short* Qg = Qb + (size_t)bh * S_SZ * HD;
    const unsigned short* Kg = Kb + (size_t)bh * S_SZ * HD;
    const unsigned short* Vg = Vt + (size_t)bh * S_SZ * HD;   // [hd][S]
    const float* mrow = mask + (size_t)b * S_SZ;

    // Q fragments straight global->reg (8 VGPRs)
    const int arow = w * 16 + col;
    bfrag aq[2];
    #pragma unroll
    for (int kk = 0; kk < 2; ++kk)
        aq[kk] = *(const bfrag*)&Qg[(size_t)(q0 + arow) * HD + (kk * 4 + quad) * 8];

    // staging geometry (shared by K and V tiles: 64 rows x 8 chunks)
    int srw[2], sgc[2];
    #pragma unroll
    for (int i = 0; i < 2; ++i) {
        int c = i * 256 + t;
        srw[i] = c >> 3;
        sgc[i] = ((c & 7) ^ (srw[i] & 7)) * 8;
    }

    // prologue: stage tile 0 into buf 0 + mask regs (set A)
    #pragma unroll
    for (int i = 0; i < 2; ++i) {
        async16(&Ks[0][(size_t)(i * 256 + wbase) * 8],
                &Kg[(size_t)srw[i] * HD + sgc[i]]);
        async16(&Vs[0][(size_t)(i * 256 + wbase) * 8],
                &Vg[(size_t)srw[i] * S_SZ + sgc[i]]);
    }
    float4 mA[4], mB[4];
    #pragma unroll
    for (int ni = 0; ni < 4; ++ni)
        mA[ni] = *(const float4*)&mrow[ni * 16 + quad * 4];

    ffrag o[4];
    #pragma unroll
    for (int i = 0; i < 4; ++i) { ffrag zf = {0.f, 0.f, 0.f, 0.f}; o[i] = zf; }
    float lsum = 0.f;
    unsigned short* Pw = &Ps[w][0];

    for (int it2 = 0; it2 < (S_SZ / 64) / 2; ++it2) {   // 16 double-iters
        attn_iter(it2 * 2 + 0, 0, Ks, Vs, Pw, Kg, Vg, mrow,
                  srw, sgc, wbase, col, quad, aq, mA, mB, o, lsum);
        attn_iter(it2 * 2 + 1, 1, Ks, Vs, Pw, Kg, Vg, mrow,
                  srw, sgc, wbase, col, quad, aq, mB, mA, o, lsum);
    }

    // l: sum the 4 quad-partials (lane holds q=w*16+col's partial)
    lsum += __shfl_xor(lsum, 16);
    lsum += __shfl_xor(lsum, 32);

    // o[di][r] is q=quad*4+r; fetch l from the lane whose col == quad*4+r
    float inv[4];
    #pragma unroll
    for (int r = 0; r < 4; ++r)
        inv[r] = 1.0f / __shfl(lsum, quad * 4 + r);
    #pragma unroll
    for (int di = 0; di < 4; ++di) {
        int d = di * 16 + col;
        #pragma unroll
        for (int r = 0; r < 4; ++r) {
            int q = q0 + w * 16 + quad * 4 + r;
            out[((size_t)(b * S_SZ + q)) * D_SZ + h * HD + d] = o[di][r] * inv[r];
        }
    }
}

// ---------------------------------------------------------------------------
extern "C" void kernel_launch(void* const* d_in, const int* in_sizes, int n_in,
                              void* d_out, int out_size, void* d_ws, size_t ws_size,
                              hipStream_t stream) {
    const float* v1   = (const float*)d_in[0];
    const float* mask = (const float*)d_in[1];
    const float* Wq   = (const float*)d_in[2];
    const float* bq   = (const float*)d_in[3];
    const float* Wk   = (const float*)d_in[4];
    const float* bk   = (const float*)d_in[5];
    const float* Wv   = (const float*)d_in[6];
    const float* bv   = (const float*)d_in[7];
    float* out = (float*)d_out;

    char* ws = (char*)d_ws;
    const size_t per_b = (size_t)BH_T * S_SZ * HD * 2;      // 6,291,456 B
    unsigned short* Qb  = (unsigned short*)(ws);
    unsigned short* Kb  = (unsigned short*)(ws + per_b);
    unsigned short* Vtb = (unsigned short*)(ws + 2 * per_b);
    unsigned short* v1b = (unsigned short*)(ws + 3 * per_b);
    unsigned short* Wt  = (unsigned short*)(ws + 3 * per_b + (size_t)M_TOT * D_SZ * 2);

    prep<<<dim3(3072 + 432), 256, 0, stream>>>(v1, Wq, Wk, Wv, v1b, Wt);
    proj_gemm<<<dim3(6, 32, 3), 256, 0, stream>>>(v1b, Wt, bq, bk, bv, Qb, Kb, Vtb);
    attn_mfma<<<dim3(32, 24), 256, 0, stream>>>(Qb, Kb, Vtb, mask, out);
}

// Round 13
// 148.407 us; speedup vs baseline: 1.0379x; 1.0379x over previous
//
// R13: R12 (attn XCD swizzle confirmed: FETCH 52.3->9.3 MB) + mask->LDS.
// Per-iter mask was 4 global float4 loads sharing the vmcnt FIFO with the
// K/V async16s (barrier drain retires them all) + mA/mB ping-pong regs.
// Now: stage the 8 KB mask row once in the prologue (async16, drained by
// iter-0's barrier), read per-iter as quad-uniform ds_read_b128 (broadcast,
// conflict-free, read-only -> race-free). LDS 40->48 KB (still 3 blocks/CU,
// grid-limited). Non-attn noise band ±5 us observed R11 vs R12 (identical
// code, 91.7 vs 98.8 us).
// Ledger: no VGPR cap (R2); V LDS-staged (R3); >=12 waves/CU (R7); BK=64
// (R8); P stride 64 (R10); V-hoist unproven-alone (R9/R10).
#include <hip/hip_runtime.h>
#include <math.h>

#define B_SZ 2
#define S_SZ 2048
#define D_SZ 768
#define NH   12
#define HD   64
#define BH_T (B_SZ * NH)      // 24
#define M_TOT (B_SZ * S_SZ)   // 4096

using bfrag = __attribute__((ext_vector_type(8))) short;   // 8 bf16 (4 VGPRs)
using ffrag = __attribute__((ext_vector_type(4))) float;   // 4 fp32 acc

__device__ __forceinline__ unsigned short f2bf(float f) {      // RNE
    unsigned int u = __float_as_uint(f);
    u += 0x7fffu + ((u >> 16) & 1u);
    return (unsigned short)(u >> 16);
}

// packed f32x2 -> bf16x2 (RNE), one VALU op. lo -> D[15:0], hi -> D[31:16].
__device__ __forceinline__ unsigned cvtpk(float lo, float hi) {
    unsigned r;
    asm("v_cvt_pk_bf16_f32 %0, %1, %2" : "=v"(r) : "v"(lo), "v"(hi));
    return r;
}

// exp2 on the VALU: v_exp_f32 computes 2^x natively; log2(e) is pre-folded
// into the Q scale (proj) and fma'd onto the mask (attn).
__device__ __forceinline__ float fexp2(float x) {
#if __has_builtin(__builtin_amdgcn_exp2f)
    return __builtin_amdgcn_exp2f(x);
#else
    float r;
    asm("v_exp_f32 %0, %1" : "=v"(r) : "v"(x));
    return r;
#endif
}

// async global->LDS, 16B per lane; no VGPR round-trip.
__device__ __forceinline__ void async16(void* lds, const void* gp) {
    __builtin_amdgcn_global_load_lds(
        (const __attribute__((address_space(1))) unsigned int*)gp,
        (__attribute__((address_space(3))) unsigned int*)lds,
        16, 0, 0);
}

// ---------------------------------------------------------------------------
// prep: fused  (a) v1 fp32->bf16   (b) W [k][n] fp32 -> Wt [n][k] bf16 x3
// ---------------------------------------------------------------------------
__global__ __launch_bounds__(256) void prep(
    const float* __restrict__ v1,
    const float* __restrict__ Wq, const float* __restrict__ Wk,
    const float* __restrict__ Wv,
    unsigned short* __restrict__ v1b, unsigned short* __restrict__ Wt) {
    __shared__ float tile[64][65];
    const int bx = blockIdx.x;
    const int t = threadIdx.x;
    if (bx < 3072) {
        int i = (bx * 256 + t) * 4;
        float4 v = *(const float4*)&v1[i];
        ushort4 o;
        o.x = f2bf(v.x); o.y = f2bf(v.y); o.z = f2bf(v.z); o.w = f2bf(v.w);
        *(ushort4*)&v1b[i] = o;
    } else {
        int r = bx - 3072;               // 0..431
        int z = r / 144;
        int rr = r % 144;
        int n0 = (rr % 12) * 64, k0 = (rr / 12) * 64;
        const float* W = (z == 0) ? Wq : (z == 1) ? Wk : Wv;
        unsigned short* dst = Wt + (size_t)z * D_SZ * D_SZ;
        #pragma unroll
        for (int i = 0; i < 16; ++i) {
            int flat = i * 256 + t;
            int rr2 = flat >> 6, c = flat & 63;
            tile[rr2][c] = W[(size_t)(k0 + rr2) * D_SZ + n0 + c];
        }
        __syncthreads();
        #pragma unroll
        for (int i = 0; i < 16; ++i) {
            int flat = i * 256 + t;
            int rr2 = flat >> 6, c = flat & 63;
            dst[(size_t)(n0 + rr2) * D_SZ + k0 + c] = f2bf(tile[c][rr2]);
        }
    }
}

// ---------------------------------------------------------------------------
// QKV projection (R11-verified): 128x128 tile, BK=64, dbuf LDS via async16,
// XCD-chunked block swizzle (576 % 8 == 0; each XCD: one z, 12 y, 6 x ->
// 3.6 MB working set fits 4 MB L2).
// z<2 (Q,K): swapped operands -> lane holds 4 consecutive n; Q scaled by
// (1/8)*log2(e). z==2 (V): lane holds 4 consecutive tokens -> V^T output.
// LDS: 2 x (A 128x64 + B 128x64) bf16 = 64 KB -> 2 blocks/CU.
// ---------------------------------------------------------------------------
#define RP_LD 136

__global__ __launch_bounds__(256) void proj_gemm(
    const unsigned short* __restrict__ Ab,    // v1 bf16 [4096][768]
    const unsigned short* __restrict__ Wt,    // [3][768 n][768 k]
    const float* __restrict__ bq, const float* __restrict__ bk_,
    const float* __restrict__ bv_,
    unsigned short* __restrict__ Qb, unsigned short* __restrict__ Kb,
    unsigned short* __restrict__ Vtb) {
    // XCD-chunked bijective swizzle (T1/m204): nwg = 576, 576 % 8 == 0.
    const int orig = blockIdx.x + 6 * blockIdx.y + 192 * blockIdx.z;
    const int wg = (orig & 7) * 72 + (orig >> 3);
    const int bxi = wg % 6;
    const int byi = (wg / 6) % 32;
    const int z = wg / 192;

    const unsigned short* Bt = Wt + (size_t)z * D_SZ * D_SZ;
    const float* bias = (z == 0) ? bq : (z == 1) ? bk_ : bv_;

    __shared__ __attribute__((aligned(16)))
        unsigned short smem[2][128 * 64 + 128 * 64];   // 64 KB dbuf
    const int t = threadIdx.x;
    const int lane = t & 63;
    const int w = t >> 6;
    const int wm = w & 1, wn = w >> 1;
    const int col = lane & 15;
    const int quad = lane >> 4;
    const int m0 = byi * 128;
    const int n0 = bxi * 128;
    const int wbase = t & ~63;

    ffrag acc[4][4];
    #pragma unroll
    for (int i = 0; i < 4; ++i)
        #pragma unroll
        for (int j = 0; j < 4; ++j) { ffrag zf = {0.f, 0.f, 0.f, 0.f}; acc[i][j] = zf; }

    // prologue: stage k0=0 into buf 0
    #pragma unroll
    for (int i = 0; i < 4; ++i) {
        int c = i * 256 + t;
        int row = c >> 3;
        int gcol = ((c & 7) ^ (row & 7)) * 8;
        async16(&smem[0][(size_t)(i * 256 + wbase) * 8],
                &Ab[(size_t)(m0 + row) * D_SZ + gcol]);
    }
    #pragma unroll
    for (int i = 0; i < 4; ++i) {
        int c = i * 256 + t;
        int row = c >> 3;
        int gcol = ((c & 7) ^ (row & 7)) * 8;
        async16(&smem[0][128 * 64 + (size_t)(i * 256 + wbase) * 8],
                &Bt[(size_t)(n0 + row) * D_SZ + gcol]);
    }

    const int nIter = D_SZ / 64;   // 12
    for (int it = 0; it < nIter; ++it) {
        const int cur = it & 1;
        __syncthreads();           // drains buf[cur] loads (full prev compute)
        if (it + 1 < nIter) {      // prefetch next panel into buf[cur^1]
            const int kn = (it + 1) * 64;
            #pragma unroll
            for (int i = 0; i < 4; ++i) {
                int c = i * 256 + t;
                int row = c >> 3;
                int gcol = ((c & 7) ^ (row & 7)) * 8;
                async16(&smem[cur ^ 1][(size_t)(i * 256 + wbase) * 8],
                        &Ab[(size_t)(m0 + row) * D_SZ + kn + gcol]);
            }
            #pragma unroll
            for (int i = 0; i < 4; ++i) {
                int c = i * 256 + t;
                int row = c >> 3;
                int gcol = ((c & 7) ^ (row & 7)) * 8;
                async16(&smem[cur ^ 1][128 * 64 + (size_t)(i * 256 + wbase) * 8],
                        &Bt[(size_t)(n0 + row) * D_SZ + kn + gcol]);
            }
        }
        const unsigned short* As = &smem[cur][0];
        const unsigned short* Bs = &smem[cur][128 * 64];
        #pragma unroll
        for (int kk = 0; kk < 64; kk += 32) {
            const int cc = (kk >> 3) + quad;
            bfrag a[4], b[4];
            #pragma unroll
            for (int mi = 0; mi < 4; ++mi) {
                int row = wm * 64 + mi * 16 + col;
                a[mi] = *(const bfrag*)&As[row * 64 + ((cc ^ (row & 7)) * 8)];
            }
            #pragma unroll
            for (int ni = 0; ni < 4; ++ni) {
                int row = wn * 64 + ni * 16 + col;
                b[ni] = *(const bfrag*)&Bs[row * 64 + ((cc ^ (row & 7)) * 8)];
            }
            if (z == 2) {
                #pragma unroll
                for (int mi = 0; mi < 4; ++mi)
                    #pragma unroll
                    for (int ni = 0; ni < 4; ++ni)
                        acc[mi][ni] = __builtin_amdgcn_mfma_f32_16x16x32_bf16(
                            a[mi], b[ni], acc[mi][ni], 0, 0, 0);
            } else {
                #pragma unroll
                for (int mi = 0; mi < 4; ++mi)
                    #pragma unroll
                    for (int ni = 0; ni < 4; ++ni)
                        acc[mi][ni] = __builtin_amdgcn_mfma_f32_16x16x32_bf16(
                            b[ni], a[mi], acc[mi][ni], 0, 0, 0);
            }
        }
    }

    __syncthreads();   // reuse smem as repack tile (128 x RP_LD shorts)
    unsigned short* rp = &smem[0][0];

    if (z < 2) {
        // Q: fold 1/sqrt(hd) * log2(e) so softmax is a bare exp2
        const float sc = (z == 0) ? 0.18033688f : 1.0f;
        #pragma unroll
        for (int mi = 0; mi < 4; ++mi) {
            int m_local = wm * 64 + mi * 16 + col;             // token
            #pragma unroll
            for (int ni = 0; ni < 4; ++ni) {
                int n_base = wn * 64 + ni * 16 + quad * 4;     // 4 consecutive n
                float4 b4 = *(const float4*)&bias[n0 + n_base];
                uint2 pk;
                pk.x = (unsigned)f2bf((acc[mi][ni][0] + b4.x) * sc) |
                       ((unsigned)f2bf((acc[mi][ni][1] + b4.y) * sc) << 16);
                pk.y = (unsigned)f2bf((acc[mi][ni][2] + b4.z) * sc) |
                       ((unsigned)f2bf((acc[mi][ni][3] + b4.w) * sc) << 16);
                *(uint2*)&rp[m_local * RP_LD + n_base] = pk;
            }
        }
        __syncthreads();
        unsigned short* Out = (z == 0) ? Qb : Kb;
        #pragma unroll
        for (int j = 0; j < 8; ++j) {           // 128 rows x 16 chunks
            int flat = j * 256 + t;
            int row = flat >> 4;                // token (0..127)
            int ch = flat & 15;                 // 16B chunk within 128 n
            uint4 vv = *(const uint4*)&rp[row * RP_LD + ch * 8];
            int m = m0 + row;
            int bb = m >> 11, s = m & 2047;
            int h = (n0 >> 6) + (ch >> 3);
            int d = (ch & 7) * 8;
            *(uint4*)&Out[((size_t)(bb * NH + h) * S_SZ + s) * HD + d] = vv;
        }
    } else {
        #pragma unroll
        for (int ni = 0; ni < 4; ++ni) {
            int n_local = wn * 64 + ni * 16 + col;             // d index (0..127)
            float bvv = bias[n0 + n_local];
            #pragma unroll
            for (int mi = 0; mi < 4; ++mi) {
                int m_base = wm * 64 + mi * 16 + quad * 4;     // 4 consecutive tokens
                uint2 pk;
                pk.x = (unsigned)f2bf(acc[mi][ni][0] + bvv) |
                       ((unsigned)f2bf(acc[mi][ni][1] + bvv) << 16);
                pk.y = (unsigned)f2bf(acc[mi][ni][2] + bvv) |
                       ((unsigned)f2bf(acc[mi][ni][3] + bvv) << 16);
                *(uint2*)&rp[n_local * RP_LD + m_base] = pk;
            }
        }
        __syncthreads();
        #pragma unroll
        for (int j = 0; j < 8; ++j) {           // 128 rows x 16 chunks
            int flat = j * 256 + t;
            int row = flat >> 4;                // n index (0..127)
            int ch = flat & 15;                 // 16B chunk within 128 tokens
            uint4 vv = *(const uint4*)&rp[row * RP_LD + ch * 8];
            int n = n0 + row;
            int h = n >> 6, d = n & 63;
            int m = m0 + ch * 8;
            int bb = m >> 11, s = m & 2047;
            *(uint4*)&Vtb[((size_t)(bb * NH + h) * HD + d) * S_SZ + s] = vv;
        }
    }
}

// ---------------------------------------------------------------------------
// Flash attention (R12-verified body + mask-in-LDS): 256 threads (4 waves x
// 16 q-rows), 64-key tiles, K/V LDS dbuf via async16, swapped QK^T, cvt_pk
// P pack, x2-unrolled loop, setprio, XCD-chunked block swizzle.
// R13: whole 8 KB mask row staged to LDS in the prologue; per-iter mask is
// a quad-uniform ds_read_b128 (broadcast), removing 4 global loads/iter
// from the vmcnt queue and the mA/mB ping-pong. LDS 48 KB (3 blocks/CU).
// ---------------------------------------------------------------------------
__device__ __forceinline__ void attn_iter(
    int it, int cur,
    unsigned short (&Ks)[2][64 * 64], unsigned short (&Vs)[2][64 * 64],
    unsigned short* Pw, const float* Msk,
    const unsigned short* Kg, const unsigned short* Vg,
    const int (&srw)[2], const int (&sgc)[2], int wbase, int col, int quad,
    const bfrag (&aq)[2], ffrag (&o)[4], float& lsum) {
    const int nIter = S_SZ / 64;
    __syncthreads();               // drains buf[cur] (loads ran during prev compute)
    if (it + 1 < nIter) {          // prefetch next tile into buf[cur^1]
        const int kn = (it + 1) * 64;
        #pragma unroll
        for (int i = 0; i < 2; ++i) {
            async16(&Ks[cur ^ 1][(size_t)(i * 256 + wbase) * 8],
                    &Kg[(size_t)(kn + srw[i]) * HD + sgc[i]]);
            async16(&Vs[cur ^ 1][(size_t)(i * 256 + wbase) * 8],
                    &Vg[(size_t)srw[i] * S_SZ + kn + sgc[i]]);
        }
    }

    // S^T = K Q^T: lane holds S[key=ni*16+quad*4+r][q=w*16+col].
    // kk=0 peeled with literal-zero C (no per-iter zero-init movs).
    ffrag s[4];
    __builtin_amdgcn_s_setprio(1);
    #pragma unroll
    for (int ni = 0; ni < 4; ++ni) {
        int brow = ni * 16 + col;
        bfrag bk0 = *(const bfrag*)&Ks[cur][brow * 64 + ((quad ^ (brow & 7)) * 8)];
        ffrag zf = {0.f, 0.f, 0.f, 0.f};
        s[ni] = __builtin_amdgcn_mfma_f32_16x16x32_bf16(bk0, aq[0], zf, 0, 0, 0);
    }
    #pragma unroll
    for (int ni = 0; ni < 4; ++ni) {
        int brow = ni * 16 + col;
        bfrag bk1 = *(const bfrag*)&Ks[cur][brow * 64 + (((4 + quad) ^ (brow & 7)) * 8)];
        s[ni] = __builtin_amdgcn_mfma_f32_16x16x32_bf16(bk1, aq[1], s[ni], 0, 0, 0);
    }
    __builtin_amdgcn_s_setprio(0);

    // p = 2^(s + m*log2e); mask from LDS (quad-uniform float4 broadcast);
    // lane-local l; pack via cvt_pk; 4 x ds_write_b64
    #pragma unroll
    for (int ni = 0; ni < 4; ++ni) {
        float4 m4 = *(const float4*)&Msk[it * 64 + ni * 16 + quad * 4];
        float p0 = fexp2(fmaf(1.44269504f, m4.x, s[ni][0]));
        float p1 = fexp2(fmaf(1.44269504f, m4.y, s[ni][1]));
        float p2 = fexp2(fmaf(1.44269504f, m4.z, s[ni][2]));
        float p3 = fexp2(fmaf(1.44269504f, m4.w, s[ni][3]));
        lsum += ((p0 + p1) + (p2 + p3));
        uint2 pkv;
        pkv.x = cvtpk(p0, p1);
        pkv.y = cvtpk(p2, p3);
        int c = ni * 2 + (quad >> 1);      // key chunk (key>>3)
        *(uint2*)&Pw[col * 64 + ((c ^ (col & 7)) * 8) + (quad & 1) * 4] = pkv;
    }

    // O += P @ V  (P read addressing identical to verified layout)
    __builtin_amdgcn_s_setprio(1);
    #pragma unroll
    for (int kk = 0; kk < 2; ++kk) {
        const int cc = kk * 4 + quad;
        bfrag ap = *(const bfrag*)&Pw[col * 64 + ((cc ^ (col & 7)) * 8)];
        #pragma unroll
        for (int di = 0; di < 4; ++di) {
            int vrow = di * 16 + col;
            bfrag bv8 = *(const bfrag*)&Vs[cur][vrow * 64 + ((cc ^ (vrow & 7)) * 8)];
            o[di] = __builtin_amdgcn_mfma_f32_16x16x32_bf16(ap, bv8, o[di], 0, 0, 0);
        }
    }
    __builtin_amdgcn_s_setprio(0);
}

__global__ __launch_bounds__(256) void attn_mfma(
    const unsigned short* __restrict__ Qb, const unsigned short* __restrict__ Kb,
    const unsigned short* __restrict__ Vt, const float* __restrict__ mask,
    float* __restrict__ out) {
    __shared__ unsigned short Ks[2][64 * 64];  // 16 KB [key][d] swizzled
    __shared__ unsigned short Vs[2][64 * 64];  // 16 KB [d][key] swizzled
    __shared__ unsigned short Ps[4][16 * 64];  // 8 KB wave-private [q][key] swz
    __shared__ __attribute__((aligned(16))) float Msk[S_SZ];  // 8 KB mask row

    const int t = threadIdx.x;
    const int lane = t & 63;
    const int w = t >> 6;
    const int col = lane & 15;
    const int quad = lane >> 4;

    // XCD-chunked bijective swizzle (nwg = 768 = 8 x 96): XCD i gets wg in
    // [96i, 96(i+1)) = heads 3i..3i+2, all 32 q-blocks of each.
    const int orig = blockIdx.x + 32 * blockIdx.y;
    const int wg = (orig & 7) * 96 + (orig >> 3);
    const int q0 = (wg & 31) * 64;
    const int bh = wg >> 5;
    const int b = bh / NH, h = bh % NH;
    const int wbase = t & ~63;

    const unsigned short* Qg = Qb + (size_t)bh * S_SZ * HD;
    const unsigned short* Kg = Kb + (size_t)bh * S_SZ * HD;
    const unsigned short* Vg = Vt + (size_t)bh * S_SZ * HD;   // [hd][S]
    const float* mrow = mask + (size_t)b * S_SZ;

    // Q fragments straight global->reg (8 VGPRs)
    const int arow = w * 16 + col;
    bfrag aq[2];
    #pragma unroll
    for (int kk = 0; kk < 2; ++kk)
        aq[kk] = *(const bfrag*)&Qg[(size_t)(q0 + arow) * HD + (kk * 4 + quad) * 8];

    // staging geometry (shared by K and V tiles: 64 rows x 8 chunks)
    int srw[2], sgc[2];
    #pragma unroll
    for (int i = 0; i < 2; ++i) {
        int c = i * 256 + t;
        srw[i] = c >> 3;
        sgc[i] = ((c & 7) ^ (srw[i] & 7)) * 8;
    }

    // prologue: stage tile 0 into buf 0 + full mask row (8 KB, once)
    #pragma unroll
    for (int i = 0; i < 2; ++i) {
        async16(&Ks[0][(size_t)(i * 256 + wbase) * 8],
                &Kg[(size_t)srw[i] * HD + sgc[i]]);
        async16(&Vs[0][(size_t)(i * 256 + wbase) * 8],
                &Vg[(size_t)srw[i] * S_SZ + sgc[i]]);
    }
    #pragma unroll
    for (int i = 0; i < 2; ++i)
        async16(&Msk[(size_t)(i * 256 + wbase) * 4],
                &mrow[(size_t)(i * 256 + t) * 4]);

    ffrag o[4];
    #pragma unroll
    for (int i = 0; i < 4; ++i) { ffrag zf = {0.f, 0.f, 0.f, 0.f}; o[i] = zf; }
    float lsum = 0.f;
    unsigned short* Pw = &Ps[w][0];

    for (int it2 = 0; it2 < (S_SZ / 64) / 2; ++it2) {   // 16 double-iters
        attn_iter(it2 * 2 + 0, 0, Ks, Vs, Pw, Msk, Kg, Vg,
                  srw, sgc, wbase, col, quad, aq, o, lsum);
        attn_iter(it2 * 2 + 1, 1, Ks, Vs, Pw, Msk, Kg, Vg,
                  srw, sgc, wbase, col, quad, aq, o, lsum);
    }

    // l: sum the 4 quad-partials (lane holds q=w*16+col's partial)
    lsum += __shfl_xor(lsum, 16);
    lsum += __shfl_xor(lsum, 32);

    // o[di][r] is q=quad*4+r; fetch l from the lane whose col == quad*4+r
    float inv[4];
    #pragma unroll
    for (int r = 0; r < 4; ++r)
        inv[r] = 1.0f / __shfl(lsum, quad * 4 + r);
    #pragma unroll
    for (int di = 0; di < 4; ++di) {
        int d = di * 16 + col;
        #pragma unroll
        for (int r = 0; r < 4; ++r) {
            int q = q0 + w * 16 + quad * 4 + r;
            out[((size_t)(b * S_SZ + q)) * D_SZ + h * HD + d] = o[di][r] * inv[r];
        }
    }
}

// ---------------------------------------------------------------------------
extern "C" void kernel_launch(void* const* d_in, const int* in_sizes, int n_in,
                              void* d_out, int out_size, void* d_ws, size_t ws_size,
                              hipStream_t stream) {
    const float* v1   = (const float*)d_in[0];
    const float* mask = (const float*)d_in[1];
    const float* Wq   = (const float*)d_in[2];
    const float* bq   = (const float*)d_in[3];
    const float* Wk   = (const float*)d_in[4];
    const float* bk   = (const float*)d_in[5];
    const float* Wv   = (const float*)d_in[6];
    const float* bv   = (const float*)d_in[7];
    float* out = (float*)d_out;

    char* ws = (char*)d_ws;
    const size_t per_b = (size_t)BH_T * S_SZ * HD * 2;      // 6,291,456 B
    unsigned short* Qb  = (unsigned short*)(ws);
    unsigned short* Kb  = (unsigned short*)(ws + per_b);
    unsigned short* Vtb = (unsigned short*)(ws + 2 * per_b);
    unsigned short* v1b = (unsigned short*)(ws + 3 * per_b);
    unsigned short* Wt  = (unsigned short*)(ws + 3 * per_b + (size_t)M_TOT * D_SZ * 2);

    prep<<<dim3(3072 + 432), 256, 0, stream>>>(v1, Wq, Wk, Wv, v1b, Wt);
    proj_gemm<<<dim3(6, 32, 3), 256, 0, stream>>>(v1b, Wt, bq, bk, bv, Qb, Kb, Vtb);
    attn_mfma<<<dim3(32, 24), 256, 0, stream>>>(Qb, Kb, Vtb, mask, out);
}